// Round 9
// baseline (240.238 us; speedup 1.0000x reference)
//
#include <hip/hip_runtime.h>
#include <math.h>
#include <limits.h>

// 4-byte-aligned vector loads: backend emits global_load_dwordx4 / dwordx2 at
// dword-aligned (not naturally-aligned) addresses — legal on CDNA.
typedef float f4u __attribute__((ext_vector_type(4), aligned(4)));
typedef float f2u __attribute__((ext_vector_type(2), aligned(4)));

#define TILE_W 64
#define TILE_H 16
#define YB 38            // max band rows (15*cH + 20.02 + 3 -> <=38, proven)
#define XBT 92           // band texels/row: need <=85 (+3 align), capacity ldx<=90
#define XBF (XBT * 3)    // 276 dwords/row: %4==0 (16B rows), %32==20 (bank spread)

// Reflection per reference: x+=0.5; x=mod(x,2S); x = x>=S ? 2S-x : x; x-=0.5; clip[0,S-1]
// Input here is already x+0.5. inv_two = 1/(2S) (exact for pow-2 S).
__device__ __forceinline__ float reflect_pre(float xr, float size, float two, float inv_two) {
    xr = xr - floorf(xr * inv_two) * two;   // floor-mod into [0, 2S)
    if (xr >= size) xr = two - xr;
    xr -= 0.5f;
    return fminf(fmaxf(xr, 0.0f), size - 1.0f);
}

// bilinear taps for one output pixel (w,h) given its dmap value dm
__device__ __forceinline__ void px_taps(int w, int h, float dm,
    float cW, float cH, float kxc, float kyc, int W, int H,
    float twoW, float twoH, float invTwoW, float invTwoH,
    int& qx, int& jy0, int& jy1, float& wx, float& wy, bool& cl)
{
    float rx = (float)w * cW + dm * kxc;    // ix + 0.5
    float ry = (float)h * cH + dm * kyc;    // iy + 0.5
    float ix = reflect_pre(rx, (float)W, twoW, invTwoW);
    float iy = reflect_pre(ry, (float)H, twoH, invTwoH);
    float x0f = floorf(ix), y0f = floorf(iy);
    wx = ix - x0f;  wy = iy - y0f;
    int ix0 = (int)x0f;                     // in [0, W-1] after clip
    jy0 = (int)y0f;
    jy1 = min(jy0 + 1, H - 1);
    qx  = min(ix0, W - 2);                  // texel pair [qx, qx+1] in-bounds
    cl  = (ix0 > qx);                       // ix0==W-1 (wx==0): tap A = texel qx+1
}

// ---------------- tiled fused kernel: 64x16 tile, LDS band, 512 threads ----
// Round-8 lesson: LDS staging's concept was right (TA lane-address work ~halves)
// but implementation taxes buried it: occupancy 35% (the lever: time ~ k/occ
// across rounds 5-8), fill VALU from dynamic bounds, 4.35M bank conflicts
// (264 % 32 == 8). Fixes: 512-thr block (2 px/thread) -> 3 blocks x 8 waves =
// 24 waves/CU (75%); fixed-shape fill (38 x 92 texels, 16B-aligned base,
// compile-time trips); XBF=276 (%32==20) bank spread.
__global__ __launch_bounds__(512, 8) void displace_tile_kernel(
    const float* __restrict__ img,     // N,H,W,3
    const float* __restrict__ dmap,    // N,DH,DW,3
    const float* __restrict__ amp,     // N
    const float* __restrict__ ang,     // N
    float* __restrict__ out,           // N,H,W,3
    int N, int H, int W, int DH, int DW,
    int tiles_x, int tiles_per_img, unsigned nb)
{
    __shared__ __align__(16) float band[YB * XBF];   // 41,952 B

    unsigned id  = blockIdx.x;
    unsigned q   = nb >> 3, r = nb & 7u;
    unsigned xcd = id & 7u, off = id >> 3;
    unsigned orig = (xcd < r) ? (xcd * (q + 1u) + off)
                              : (r * (q + 1u) + (xcd - r) * q + off);

    int n    = (int)(orig / (unsigned)tiles_per_img);
    int rem  = (int)(orig % (unsigned)tiles_per_img);
    int ty_t = rem / tiles_x;
    int tx_t = rem % tiles_x;

    int lane = (int)(threadIdx.x & 63u);
    int warp = (int)(threadIdx.x >> 6u);    // 0..7

    int x0 = tx_t * TILE_W;
    int hT = ty_t * TILE_H;
    int w  = x0 + lane;                     // global x (wave = 64 adjacent px)
    int h0 = hT + warp * 2;                 // even always

    // ---- dmap loads FIRST: rows M-1..M+1, x-texels qd,qd+1 ----
    // h0 even: px h0   -> y-taps (M-1, M, ty=.75); px h0+1 -> (M, M+1, ty=.25)
    int M  = h0 >> 1;
    int fx = (w >> 1) - 1 + (w & 1);
    float txd = (w & 1) ? 0.25f : 0.75f;
    int qd = min(max(fx, 0), DW - 2);
    bool hiA = (fx >= DW - 1);
    bool loB = (fx < 0);

    const float* dbase = dmap + (long long)n * DH * DW * 3;
    f4u dv[3]; f2u du[3];
    #pragma unroll
    for (int j = 0; j < 3; ++j) {
        int rj = min(max(M - 1 + j, 0), DH - 1);
        const float* pr = dbase + ((long long)rj * DW + qd) * 3;
        dv[j] = *(const f4u*)pr;
        du[j] = *(const f2u*)(pr + 4);
    }

    // ---- per-image constants (overlap dmap latency) ----
    float a = amp[n];
    float sa, ca;
    sincosf(ang[n], &sa, &ca);
    float cW = (float)W / (float)(W - 1);
    float cH = (float)H / (float)(H - 1);
    float kxc = ca * a * cW;
    float kyc = sa * a * cH;
    float twoW = 2.0f * (float)W, twoH = 2.0f * (float)H;
    float invTwoW = 1.0f / twoW, invTwoH = 1.0f / twoH;
    const float s3 = 1.0f / 3.0f;

    // ---- band bounds (block-uniform; dm in [0,1]; reflect handled) ----
    float ixmin = (float)x0 * cW - 0.5f + fminf(0.0f, kxc);
    float ixmax = (float)(x0 + TILE_W - 1) * cW - 0.5f + fmaxf(0.0f, kxc);
    float iymin = (float)hT * cH - 0.5f + fminf(0.0f, kyc);
    float iymax = (float)(hT + TILE_H - 1) * cH - 0.5f + fmaxf(0.0f, kyc);

    int xlo = (int)floorf(ixmin);
    int xhi = (int)floorf(ixmax) + 1;
    if (ixmin < -0.5f)            xhi = max(xhi, (int)floorf(-ixmin - 1.0f) + 1);
    if (ixmax > (float)W - 0.5f)  xlo = min(xlo, (int)floorf(twoW - ixmax - 1.0f));
    xlo = max(0, xlo);  xhi = min(W - 1, xhi);

    int ylo = (int)floorf(iymin);
    int yhi = (int)floorf(iymax) + 1;
    if (iymin < -0.5f)            yhi = max(yhi, (int)floorf(-iymin - 1.0f) + 1);
    if (iymax > (float)H - 0.5f)  ylo = min(ylo, (int)floorf(twoH - iymax - 1.0f));
    ylo = max(0, ylo);  yhi = min(H - 1, yhi);

    int cols  = xhi - xlo + 1;
    int rowsn = yhi - ylo + 1;
    bool ok = (cols <= XBT - 4) && (rowsn <= YB);   // capacity incl. align slack

    const float* ibase = img + (long long)n * H * W * 3;

    // ---- Rr: x-interp of per-row dmap channel-sum ----
    float Rr[3];
    #pragma unroll
    for (int j = 0; j < 3; ++j) {
        float mlo = dv[j].x + dv[j].y + dv[j].z;
        float mhi = dv[j].w + du[j].x + du[j].y;
        float A = hiA ? mhi : mlo;
        float B = loB ? mlo : mhi;
        Rr[j] = A + txd * (B - A);
    }
    const float tyv[2] = {0.75f, 0.25f};

    if (ok) {
        // fixed 92-texel window, 16B-aligned global base
        int xlo_f = xlo & ~3;
        xlo_f = min(xlo_f, W - XBT);
        xlo_f = max(xlo_f, 0);
        int ylo_f = min(ylo, H - YB);
        ylo_f = max(ylo_f, 0);
        // coverage: xlo_f <= xlo (or tail window spans [W-92,W-1] superset),
        // xlo_f+91 >= xhi; ylo_f <= ylo, ylo_f+37 >= yhi (rowsn<=38 proven).

        // ---- fill: 38 rows x 69 float4-chunks, fixed trips, coalesced ----
        const float* gb = ibase + ((long long)ylo_f * W + xlo_f) * 3;
        #pragma unroll
        for (int rr = 0; rr < 5; ++rr) {
            int row = warp + rr * 8;
            if (row < YB) {
                const float* g = gb + (long long)row * W * 3;   // 16B-aligned
                float* l = band + row * XBF;
                *(float4*)(l + 4 * lane) = *(const float4*)(g + 4 * lane);
                if (lane < (XBF / 4 - 64)) {                    // 5 tail chunks
                    *(float4*)(l + 256 + 4 * lane) = *(const float4*)(g + 256 + 4 * lane);
                }
            }
        }
        __syncthreads();

        // ---- taps (2 px) ----
        int b0[2], b1[2]; float wxv[2], wyv[2]; bool CL[2];
        #pragma unroll
        for (int p = 0; p < 2; ++p) {
            float Ra = Rr[p], Rb = Rr[p + 1];
            float dm = (Ra + tyv[p] * (Rb - Ra)) * s3;
            int qx, jy0, jy1; float wx, wy; bool cl;
            px_taps(w, h0 + p, dm, cW, cH, kxc, kyc, W, H,
                    twoW, twoH, invTwoW, invTwoH, qx, jy0, jy1, wx, wy, cl);
            int ldx = min(max(qx - xlo_f, 0), XBT - 2);     // defensive clamps
            int ly0 = min(max(jy0 - ylo_f, 0), YB - 1);
            int ly1 = min(max(jy1 - ylo_f, 0), YB - 1);
            b0[p] = ly0 * XBF + ldx * 3;
            b1[p] = ly1 * XBF + ldx * 3;
            wxv[p] = wx; wyv[p] = wy; CL[p] = cl;
        }

        float t0[2][6], t1[2][6];
        #pragma unroll
        for (int p = 0; p < 2; ++p) {
            #pragma unroll
            for (int j = 0; j < 6; ++j) {
                t0[p][j] = band[b0[p] + j];
                t1[p][j] = band[b1[p] + j];
            }
        }

        #pragma unroll
        for (int p = 0; p < 2; ++p) {
            float wx = wxv[p], wy = wyv[p];
            float wa = (1.0f - wx) * (1.0f - wy);
            float wb = wx * (1.0f - wy);
            float wc = (1.0f - wx) * wy;
            float wd = wx * wy;
            bool cl = CL[p];
            float A0 = cl ? t0[p][3] : t0[p][0], A1 = cl ? t0[p][4] : t0[p][1], A2 = cl ? t0[p][5] : t0[p][2];
            float B0 = t0[p][3],                 B1 = t0[p][4],                 B2 = t0[p][5];
            float C0 = cl ? t1[p][3] : t1[p][0], C1 = cl ? t1[p][4] : t1[p][1], C2 = cl ? t1[p][5] : t1[p][2];
            float D0 = t1[p][3],                 D1 = t1[p][4],                 D2 = t1[p][5];
            float* o = out + (((long long)(n * H + h0 + p)) * W + w) * 3;
            f2u s2; s2.x = A0 * wa + B0 * wb + C0 * wc + D0 * wd;
            s2.y = A1 * wa + B1 * wb + C1 * wc + D1 * wd;
            *(f2u*)o = s2;
            o[2] = A2 * wa + B2 * wb + C2 * wc + D2 * wd;
        }
    } else {
        // ---- block-uniform fallback: verified direct-gather path (2 px) ----
        #pragma unroll
        for (int p = 0; p < 2; ++p) {
            float Ra = Rr[p], Rb = Rr[p + 1];
            float dm = (Ra + tyv[p] * (Rb - Ra)) * s3;
            int qx, jy0, jy1; float wx, wy; bool cl;
            px_taps(w, h0 + p, dm, cW, cH, kxc, kyc, W, H,
                    twoW, twoH, invTwoW, invTwoH, qx, jy0, jy1, wx, wy, cl);
            const float* PA = ibase + ((long long)jy0 * W + qx) * 3;
            const float* PB = ibase + ((long long)jy1 * W + qx) * 3;
            f4u va = *(const f4u*)PA;  f2u ua = *(const f2u*)(PA + 4);
            f4u vb = *(const f4u*)PB;  f2u ub = *(const f2u*)(PB + 4);
            float wa = (1.0f - wx) * (1.0f - wy);
            float wb = wx * (1.0f - wy);
            float wc = (1.0f - wx) * wy;
            float wd = wx * wy;
            float A0 = cl ? va.w : va.x, A1 = cl ? ua.x : va.y, A2 = cl ? ua.y : va.z;
            float B0 = va.w,             B1 = ua.x,             B2 = ua.y;
            float C0 = cl ? vb.w : vb.x, C1 = cl ? ub.x : vb.y, C2 = cl ? ub.y : vb.z;
            float D0 = vb.w,             D1 = ub.x,             D2 = ub.y;
            float* o = out + (((long long)(n * H + h0 + p)) * W + w) * 3;
            f2u s2; s2.x = A0 * wa + B0 * wb + C0 * wc + D0 * wd;
            s2.y = A1 * wa + B1 * wb + C1 * wc + D1 * wd;
            *(f2u*)o = s2;
            o[2] = A2 * wa + B2 * wb + C2 * wc + D2 * wd;
        }
    }
}

// ---------------- fallback: verified single-pixel kernel ----------------
__device__ __forceinline__ float reflect_coord(float x, float size) {
    x += 0.5f;
    float two = 2.0f * size;
    x = x - floorf(x / two) * two;
    if (x >= size) x = two - x;
    x -= 0.5f;
    return fminf(fmaxf(x, 0.0f), size - 1.0f);
}

__global__ __launch_bounds__(256) void displace_kernel(
    const float* __restrict__ img, const float* __restrict__ dmap,
    const float* __restrict__ amp, const float* __restrict__ ang,
    float* __restrict__ out, int N, int H, int W, int DH, int DW)
{
    long long idx = (long long)blockIdx.x * blockDim.x + threadIdx.x;
    long long total = (long long)N * H * W;
    if (idx >= total) return;
    int w = (int)(idx % W);
    long long t = idx / W;
    int h = (int)(t % H);
    int n = (int)(t / H);

    float sx = (w + 0.5f) * ((float)DW / (float)W) - 0.5f;
    float sy = (h + 0.5f) * ((float)DH / (float)H) - 0.5f;
    float fx = floorf(sx), fy = floorf(sy);
    float tx = sx - fx, ty = sy - fy;
    int dx0 = max(0, min(DW - 1, (int)fx));
    int dx1 = max(0, min(DW - 1, (int)fx + 1));
    int dy0 = max(0, min(DH - 1, (int)fy));
    int dy1 = max(0, min(DH - 1, (int)fy + 1));

    const float* dbase = dmap + (long long)n * DH * DW * 3;
    const float* p00 = dbase + ((long long)dy0 * DW + dx0) * 3;
    const float* p01 = dbase + ((long long)dy0 * DW + dx1) * 3;
    const float* p10 = dbase + ((long long)dy1 * DW + dx0) * 3;
    const float* p11 = dbase + ((long long)dy1 * DW + dx1) * 3;
    float m00 = p00[0] + p00[1] + p00[2];
    float m01 = p01[0] + p01[1] + p01[2];
    float m10 = p10[0] + p10[1] + p10[2];
    float m11 = p11[0] + p11[1] + p11[2];
    float dmv = ((m00 * (1.0f - tx) + m01 * tx) * (1.0f - ty)
               + (m10 * (1.0f - tx) + m11 * tx) * ty) * (1.0f / 3.0f);

    float a = amp[n];
    float sa, ca;
    sincosf(ang[n], &sa, &ca);
    float d = dmv * a;
    float ddx = ca * d * (2.0f / (float)(W - 1));
    float ddy = sa * d * (2.0f / (float)(H - 1));
    float gx = -1.0f + 2.0f * (float)w / (float)(W - 1) + ddx;
    float gy = -1.0f + 2.0f * (float)h / (float)(H - 1) + ddy;
    float ix = ((gx + 1.0f) * (float)W - 1.0f) * 0.5f;
    float iy = ((gy + 1.0f) * (float)H - 1.0f) * 0.5f;
    ix = reflect_coord(ix, (float)W);
    iy = reflect_coord(iy, (float)H);

    float x0f = floorf(ix), y0f = floorf(iy);
    float wx = ix - x0f, wy = iy - y0f;
    int ix0 = min((int)x0f, W - 1);
    int ix1 = min((int)x0f + 1, W - 1);
    int iy0 = min((int)y0f, H - 1);
    int iy1 = min((int)y0f + 1, H - 1);

    const float* ibase = img + (long long)n * H * W * 3;
    const float* Ia = ibase + ((long long)iy0 * W + ix0) * 3;
    const float* Ib = ibase + ((long long)iy0 * W + ix1) * 3;
    const float* Ic = ibase + ((long long)iy1 * W + ix0) * 3;
    const float* Id = ibase + ((long long)iy1 * W + ix1) * 3;
    float wa = (1.0f - wx) * (1.0f - wy);
    float wb = wx * (1.0f - wy);
    float wc = (1.0f - wx) * wy;
    float wd = wx * wy;
    float* o = out + idx * 3;
    #pragma unroll
    for (int c = 0; c < 3; ++c)
        o[c] = Ia[c] * wa + Ib[c] * wb + Ic[c] * wc + Id[c] * wd;
}

extern "C" void kernel_launch(void* const* d_in, const int* in_sizes, int n_in,
                              void* d_out, int out_size, void* d_ws, size_t ws_size,
                              hipStream_t stream) {
    const float* img  = (const float*)d_in[0];
    const float* dmap = (const float*)d_in[1];
    const float* amp  = (const float*)d_in[2];
    const float* ang  = (const float*)d_in[3];
    float* out = (float*)d_out;

    int N = in_sizes[2];
    long long hw  = (long long)in_sizes[0] / ((long long)N * 3);
    int H = (int)llround(sqrt((double)hw));
    int W = H;
    long long dhw = (long long)in_sizes[1] / ((long long)N * 3);
    int DH = (int)llround(sqrt((double)dhw));
    int DW = DH;

    bool fast = (W % 64 == 0) && (H % 16 == 0) && (W == 2 * DW) && (H == 2 * DH) &&
                (DW >= 2) && (W >= 128) && (H >= 64) &&
                ((long long)H * W <= (long long)INT_MAX);

    if (fast) {
        int tiles_x = W / TILE_W;
        int tiles_y = H / TILE_H;
        int tpi = tiles_x * tiles_y;
        unsigned nb = (unsigned)((long long)tpi * N);
        displace_tile_kernel<<<nb, 512, 0, stream>>>(
            img, dmap, amp, ang, out, N, H, W, DH, DW, tiles_x, tpi, nb);
    } else {
        long long total = (long long)N * H * W;
        int block = 256;
        long long grid = (total + block - 1) / block;
        displace_kernel<<<(dim3)(unsigned)grid, block, 0, stream>>>(
            img, dmap, amp, ang, out, N, H, W, DH, DW);
    }
}

// Round 10
// 215.509 us; speedup vs baseline: 1.1147x; 1.1147x over previous
//
#include <hip/hip_runtime.h>
#include <math.h>
#include <limits.h>

// 4-byte-aligned vector loads: backend emits global_load_dwordx4 / dwordx2 at
// dword-aligned (not naturally-aligned) addresses — legal on CDNA.
typedef float f4u __attribute__((ext_vector_type(4), aligned(4)));
typedef float f2u __attribute__((ext_vector_type(2), aligned(4)));

// Reflection per reference: x+=0.5; x=mod(x,2S); x = x>=S ? 2S-x : x; x-=0.5; clip[0,S-1]
// Input here is already x+0.5. inv_two = 1/(2S) (exact for pow-2 S).
__device__ __forceinline__ float reflect_pre(float xr, float size, float two, float inv_two) {
    xr = xr - floorf(xr * inv_two) * two;   // floor-mod into [0, 2S)
    if (xr >= size) xr = two - xr;
    xr -= 0.5f;
    return fminf(fmaxf(xr, 0.0f), size - 1.0f);
}

// ---------------- tiled fused kernel: 64x16 tile, 4 vertical px per thread ----
// R6 structure (best verified: 76.4us). R8/R9 refuted the LDS-staging and
// occupancy theories (occ 35->60% made it WORSE). Remaining untested theory:
// R6's "batch 16 gathers" never reached the ISA (VGPR=40 -> backend reused dest
// regs, serializing into ~4-load waitcnt rounds; launch_bounds didn't change it).
// This round: stage 3 issues all 16 gathers as ORDERED asm volatile loads with
// early-clobber dests (RA must keep 48 result VGPRs live), one vmcnt(0) +
// sched_barrier(0) (guide rule 18) before blends -> true 16-deep MLP per wave.
// Discriminates latency-serialization (predict ~50-58us) vs TA-throughput
// (predict null ~75us -> R6 is the plateau).
__global__ __launch_bounds__(256, 4) void displace_tile_kernel(
    const float* __restrict__ img,     // N,H,W,3
    const float* __restrict__ dmap,    // N,DH,DW,3
    const float* __restrict__ amp,     // N
    const float* __restrict__ ang,     // N
    float* __restrict__ out,           // N,H,W,3
    int N, int H, int W, int DH, int DW,
    int tiles_x, int tiles_per_img, unsigned nb)
{
    unsigned id  = blockIdx.x;
    unsigned q   = nb >> 3, r = nb & 7u;
    unsigned xcd = id & 7u, off = id >> 3;
    unsigned orig = (xcd < r) ? (xcd * (q + 1u) + off)
                              : (r * (q + 1u) + (xcd - r) * q + off);

    int n    = (int)(orig / (unsigned)tiles_per_img);
    int rem  = (int)(orig % (unsigned)tiles_per_img);
    int ty_t = rem / tiles_x;
    int tx_t = rem % tiles_x;

    int lane = (int)(threadIdx.x & 63u);
    int warp = (int)(threadIdx.x >> 6u);

    int w  = tx_t * 64 + lane;          // global x (one wave = 64 adjacent px)
    int h0 = ty_t * 16 + warp * 4;      // even always

    // ---- stage 1: dmap row loads FIRST (latency overlapped by trig below) ----
    int M  = h0 >> 1;
    int fx = (w >> 1) - 1 + (w & 1);
    float tx = (w & 1) ? 0.25f : 0.75f;
    int qd = min(max(fx, 0), DW - 2);
    bool hiA = (fx >= DW - 1);
    bool loB = (fx < 0);

    const float* dbase = dmap + (long long)n * DH * DW * 3;
    f4u dv[4]; f2u du[4];
    #pragma unroll
    for (int j = 0; j < 4; ++j) {
        int rj = min(max(M - 1 + j, 0), DH - 1);
        const float* pr = dbase + ((long long)rj * DW + qd) * 3;
        dv[j] = *(const f4u*)pr;
        du[j] = *(const f2u*)(pr + 4);
    }

    // ---- per-image constants (independent of dmap loads -> overlaps) ----
    float a = amp[n];
    float sa, ca;
    sincosf(ang[n], &sa, &ca);
    float cW = (float)W / (float)(W - 1);
    float cH = (float)H / (float)(H - 1);
    float kxc = ca * a * cW;            // d(ix+0.5)/d(dm)
    float kyc = sa * a * cH;
    float twoW = 2.0f * (float)W, twoH = 2.0f * (float)H;
    float invTwoW = 1.0f / twoW, invTwoH = 1.0f / twoH;
    const float s3 = 1.0f / 3.0f;

    // ---- Rr: x-interp of per-row channel-sum ----
    float Rr[4];
    #pragma unroll
    for (int j = 0; j < 4; ++j) {
        float mlo = dv[j].x + dv[j].y + dv[j].z;
        float mhi = dv[j].w + du[j].x + du[j].y;
        float A = hiA ? mhi : mlo;
        float B = loB ? mlo : mhi;
        Rr[j] = A + tx * (B - A);
    }

    float wxv[4], wyv[4];
    const float* PA[4];
    const float* PB[4];
    bool  CL[4];
    const float* ibase = img + (long long)n * H * W * 3;

    // y-tap table for h0 even
    const int   jlo[4] = {0, 1, 1, 2};
    const float tyv[4] = {0.75f, 0.25f, 0.75f, 0.25f};

    // ---- stage 2: all addresses/weights (no loads) ----
    #pragma unroll
    for (int p = 0; p < 4; ++p) {
        float Ra = Rr[jlo[p]], Rb = Rr[jlo[p] + 1];
        float dm = (Ra + tyv[p] * (Rb - Ra)) * s3;

        float rx = (float)w * cW        + dm * kxc;   // ix + 0.5
        float ry = (float)(h0 + p) * cH + dm * kyc;   // iy + 0.5
        float ix = reflect_pre(rx, (float)W, twoW, invTwoW);
        float iy = reflect_pre(ry, (float)H, twoH, invTwoH);

        float x0f = floorf(ix), y0f = floorf(iy);
        wxv[p] = ix - x0f;
        wyv[p] = iy - y0f;
        int ix0 = (int)x0f;                 // in [0, W-1] after clip
        int jy0 = (int)y0f;
        int jy1 = min(jy0 + 1, H - 1);
        int qx  = min(ix0, W - 2);          // pair window always in-bounds
        CL[p] = (ix0 > qx);                 // ix0==W-1 -> wx==0, A:=texel W-1
        PA[p] = ibase + ((long long)jy0 * W + qx) * 3;
        PB[p] = ibase + ((long long)jy1 * W + qx) * 3;
    }

    // ---- stage 3: ALL 16 gathers as ORDERED volatile asm (true 16-deep MLP) ----
    f4u va[4], vb[4]; f2u ua[4], ub[4];
    #pragma unroll
    for (int p = 0; p < 4; ++p) {
        asm volatile("global_load_dwordx4 %0, %1, off"
                     : "=&v"(va[p]) : "v"(PA[p]));
        asm volatile("global_load_dwordx2 %0, %1, off"
                     : "=&v"(ua[p]) : "v"(PA[p] + 4));
        asm volatile("global_load_dwordx4 %0, %1, off"
                     : "=&v"(vb[p]) : "v"(PB[p]));
        asm volatile("global_load_dwordx2 %0, %1, off"
                     : "=&v"(ub[p]) : "v"(PB[p] + 4));
    }
    asm volatile("s_waitcnt vmcnt(0)" ::: "memory");
    __builtin_amdgcn_sched_barrier(0);      // rule 18: no use hoisted above the wait

    // ---- stage 4: blend + store ----
    long long obase = ((long long)(n * H + h0) * W + w) * 3;
    #pragma unroll
    for (int p = 0; p < 4; ++p) {
        float wx = wxv[p], wy = wyv[p];
        float wa = (1.0f - wx) * (1.0f - wy);
        float wb = wx * (1.0f - wy);
        float wc = (1.0f - wx) * wy;
        float wd = wx * wy;
        bool cl = CL[p];

        float A0 = cl ? va[p].w : va[p].x, A1 = cl ? ua[p].x : va[p].y, A2 = cl ? ua[p].y : va[p].z;
        float B0 = va[p].w,                B1 = ua[p].x,                B2 = ua[p].y;
        float C0 = cl ? vb[p].w : vb[p].x, C1 = cl ? ub[p].x : vb[p].y, C2 = cl ? ub[p].y : vb[p].z;
        float D0 = vb[p].w,                D1 = ub[p].x,                D2 = ub[p].y;

        float* o = out + obase + (long long)p * W * 3;
        o[0] = A0 * wa + B0 * wb + C0 * wc + D0 * wd;
        o[1] = A1 * wa + B1 * wb + C1 * wc + D1 * wd;
        o[2] = A2 * wa + B2 * wb + C2 * wc + D2 * wd;
    }
}

// ---------------- fallback: verified single-pixel kernel ----------------
__device__ __forceinline__ float reflect_coord(float x, float size) {
    x += 0.5f;
    float two = 2.0f * size;
    x = x - floorf(x / two) * two;
    if (x >= size) x = two - x;
    x -= 0.5f;
    return fminf(fmaxf(x, 0.0f), size - 1.0f);
}

__global__ __launch_bounds__(256) void displace_kernel(
    const float* __restrict__ img, const float* __restrict__ dmap,
    const float* __restrict__ amp, const float* __restrict__ ang,
    float* __restrict__ out, int N, int H, int W, int DH, int DW)
{
    long long idx = (long long)blockIdx.x * blockDim.x + threadIdx.x;
    long long total = (long long)N * H * W;
    if (idx >= total) return;
    int w = (int)(idx % W);
    long long t = idx / W;
    int h = (int)(t % H);
    int n = (int)(t / H);

    float sx = (w + 0.5f) * ((float)DW / (float)W) - 0.5f;
    float sy = (h + 0.5f) * ((float)DH / (float)H) - 0.5f;
    float fx = floorf(sx), fy = floorf(sy);
    float tx = sx - fx, ty = sy - fy;
    int dx0 = max(0, min(DW - 1, (int)fx));
    int dx1 = max(0, min(DW - 1, (int)fx + 1));
    int dy0 = max(0, min(DH - 1, (int)fy));
    int dy1 = max(0, min(DH - 1, (int)fy + 1));

    const float* dbase = dmap + (long long)n * DH * DW * 3;
    const float* p00 = dbase + ((long long)dy0 * DW + dx0) * 3;
    const float* p01 = dbase + ((long long)dy0 * DW + dx1) * 3;
    const float* p10 = dbase + ((long long)dy1 * DW + dx0) * 3;
    const float* p11 = dbase + ((long long)dy1 * DW + dx1) * 3;
    float m00 = p00[0] + p00[1] + p00[2];
    float m01 = p01[0] + p01[1] + p01[2];
    float m10 = p10[0] + p10[1] + p10[2];
    float m11 = p11[0] + p11[1] + p11[2];
    float dmv = ((m00 * (1.0f - tx) + m01 * tx) * (1.0f - ty)
               + (m10 * (1.0f - tx) + m11 * tx) * ty) * (1.0f / 3.0f);

    float a = amp[n];
    float sa, ca;
    sincosf(ang[n], &sa, &ca);
    float d = dmv * a;
    float ddx = ca * d * (2.0f / (float)(W - 1));
    float ddy = sa * d * (2.0f / (float)(H - 1));
    float gx = -1.0f + 2.0f * (float)w / (float)(W - 1) + ddx;
    float gy = -1.0f + 2.0f * (float)h / (float)(H - 1) + ddy;
    float ix = ((gx + 1.0f) * (float)W - 1.0f) * 0.5f;
    float iy = ((gy + 1.0f) * (float)H - 1.0f) * 0.5f;
    ix = reflect_coord(ix, (float)W);
    iy = reflect_coord(iy, (float)H);

    float x0f = floorf(ix), y0f = floorf(iy);
    float wx = ix - x0f, wy = iy - y0f;
    int ix0 = min((int)x0f, W - 1);
    int ix1 = min((int)x0f + 1, W - 1);
    int iy0 = min((int)y0f, H - 1);
    int iy1 = min((int)y0f + 1, H - 1);

    const float* ibase = img + (long long)n * H * W * 3;
    const float* Ia = ibase + ((long long)iy0 * W + ix0) * 3;
    const float* Ib = ibase + ((long long)iy0 * W + ix1) * 3;
    const float* Ic = ibase + ((long long)iy1 * W + ix0) * 3;
    const float* Id = ibase + ((long long)iy1 * W + ix1) * 3;
    float wa = (1.0f - wx) * (1.0f - wy);
    float wb = wx * (1.0f - wy);
    float wc = (1.0f - wx) * wy;
    float wd = wx * wy;
    float* o = out + idx * 3;
    #pragma unroll
    for (int c = 0; c < 3; ++c)
        o[c] = Ia[c] * wa + Ib[c] * wb + Ic[c] * wc + Id[c] * wd;
}

extern "C" void kernel_launch(void* const* d_in, const int* in_sizes, int n_in,
                              void* d_out, int out_size, void* d_ws, size_t ws_size,
                              hipStream_t stream) {
    const float* img  = (const float*)d_in[0];
    const float* dmap = (const float*)d_in[1];
    const float* amp  = (const float*)d_in[2];
    const float* ang  = (const float*)d_in[3];
    float* out = (float*)d_out;

    int N = in_sizes[2];
    long long hw  = (long long)in_sizes[0] / ((long long)N * 3);
    int H = (int)llround(sqrt((double)hw));
    int W = H;
    long long dhw = (long long)in_sizes[1] / ((long long)N * 3);
    int DH = (int)llround(sqrt((double)dhw));
    int DW = DH;

    bool fast = (W % 64 == 0) && (H % 16 == 0) && (W == 2 * DW) && (H == 2 * DH) &&
                (DW >= 2) && ((long long)H * W <= (long long)INT_MAX);

    if (fast) {
        int tiles_x = W / 64;
        int tiles_y = H / 16;
        int tpi = tiles_x * tiles_y;
        unsigned nb = (unsigned)((long long)tpi * N);
        displace_tile_kernel<<<nb, 256, 0, stream>>>(
            img, dmap, amp, ang, out, N, H, W, DH, DW, tiles_x, tpi, nb);
    } else {
        long long total = (long long)N * H * W;
        int block = 256;
        long long grid = (total + block - 1) / block;
        displace_kernel<<<(dim3)(unsigned)grid, block, 0, stream>>>(
            img, dmap, amp, ang, out, N, H, W, DH, DW);
    }
}

// Round 11
// 208.738 us; speedup vs baseline: 1.1509x; 1.0324x over previous
//
#include <hip/hip_runtime.h>
#include <math.h>
#include <limits.h>

// 4-byte-aligned vector loads: backend emits global_load_dwordx4 / dwordx2 at
// dword-aligned (not naturally-aligned) addresses — legal on CDNA.
typedef float f4u __attribute__((ext_vector_type(4), aligned(4)));
typedef float f2u __attribute__((ext_vector_type(2), aligned(4)));

// Reflection per reference: x+=0.5; x=mod(x,2S); x = x>=S ? 2S-x : x; x-=0.5; clip[0,S-1]
// Input here is already x+0.5. inv_two = 1/(2S) (exact for pow-2 S).
__device__ __forceinline__ float reflect_pre(float xr, float size, float two, float inv_two) {
    xr = xr - floorf(xr * inv_two) * two;   // floor-mod into [0, 2S)
    if (xr >= size) xr = two - xr;
    xr -= 0.5f;
    return fminf(fmaxf(xr, 0.0f), size - 1.0f);
}

// ---------------- tiled fused kernel: 64x16 tile, 4 vertical px per thread ----
// FINAL: best verified configuration (76.4us kernel, round 6). Session ladder:
//   152us (4px/thread flat) -> 165 (fused, XCD swizzle: FETCH 401->61MB)
//   -> 76.4 (64x16 tile: wave = 64 x-adjacent px, lane-dense gathers)
// Refuted alternatives: LDS band staging (94, 111us: VALU+LDS replacement cost
// exceeds TA saving), occupancy raise 35->60% (worse), asm-batched 16-deep loads
// (82.5us: RA spills batch to scratch, VGPR pinned at 36).
// Structural floor: 24 VMEM instr/thread is the fp32-RGB minimum; data-driven
// lane scatter (~1 line/lane/gather) -> TA ~55us + VALU overlap ~= 76us.
__global__ __launch_bounds__(256) void displace_tile_kernel(
    const float* __restrict__ img,     // N,H,W,3
    const float* __restrict__ dmap,    // N,DH,DW,3
    const float* __restrict__ amp,     // N
    const float* __restrict__ ang,     // N
    float* __restrict__ out,           // N,H,W,3
    int N, int H, int W, int DH, int DW,
    int tiles_x, int tiles_per_img, unsigned nb)
{
    unsigned id  = blockIdx.x;
    unsigned q   = nb >> 3, r = nb & 7u;
    unsigned xcd = id & 7u, off = id >> 3;
    unsigned orig = (xcd < r) ? (xcd * (q + 1u) + off)
                              : (r * (q + 1u) + (xcd - r) * q + off);

    int n    = (int)(orig / (unsigned)tiles_per_img);
    int rem  = (int)(orig % (unsigned)tiles_per_img);
    int ty_t = rem / tiles_x;
    int tx_t = rem % tiles_x;

    int lane = (int)(threadIdx.x & 63u);
    int warp = (int)(threadIdx.x >> 6u);

    int w  = tx_t * 64 + lane;          // global x (one wave = 64 adjacent px)
    int h0 = ty_t * 16 + warp * 4;      // even always

    // ---- stage 1: dmap row loads FIRST (latency overlapped by trig below) ----
    // h0 even => y-taps (M-1,M,.75)(M,M+1,.25)(M,M+1,.75)(M+1,M+2,.25), M=h0/2.
    // x: sx=0.5w-0.25 -> fx=(w>>1)-1+(w&1), tx=.75/.25.
    int M  = h0 >> 1;
    int fx = (w >> 1) - 1 + (w & 1);
    float tx = (w & 1) ? 0.25f : 0.75f;
    int qd = min(max(fx, 0), DW - 2);
    bool hiA = (fx >= DW - 1);
    bool loB = (fx < 0);

    const float* dbase = dmap + (long long)n * DH * DW * 3;
    f4u dv[4]; f2u du[4];
    #pragma unroll
    for (int j = 0; j < 4; ++j) {
        int rj = min(max(M - 1 + j, 0), DH - 1);
        const float* pr = dbase + ((long long)rj * DW + qd) * 3;
        dv[j] = *(const f4u*)pr;
        du[j] = *(const f2u*)(pr + 4);
    }

    // ---- per-image constants (independent of dmap loads -> overlaps) ----
    float a = amp[n];
    float sa, ca;
    sincosf(ang[n], &sa, &ca);
    float cW = (float)W / (float)(W - 1);
    float cH = (float)H / (float)(H - 1);
    float kxc = ca * a * cW;            // d(ix+0.5)/d(dm)
    float kyc = sa * a * cH;
    float twoW = 2.0f * (float)W, twoH = 2.0f * (float)H;
    float invTwoW = 1.0f / twoW, invTwoH = 1.0f / twoH;
    const float s3 = 1.0f / 3.0f;

    // ---- Rr: x-interp of per-row channel-sum ----
    float Rr[4];
    #pragma unroll
    for (int j = 0; j < 4; ++j) {
        float mlo = dv[j].x + dv[j].y + dv[j].z;
        float mhi = dv[j].w + du[j].x + du[j].y;
        float A = hiA ? mhi : mlo;
        float B = loB ? mlo : mhi;
        Rr[j] = A + tx * (B - A);
    }

    float wxv[4], wyv[4];
    const float* PA[4];
    const float* PB[4];
    bool  CL[4];
    const float* ibase = img + (long long)n * H * W * 3;

    // y-tap table for h0 even
    const int   jlo[4] = {0, 1, 1, 2};
    const float tyv[4] = {0.75f, 0.25f, 0.75f, 0.25f};

    // ---- stage 2: all addresses/weights (no loads) ----
    #pragma unroll
    for (int p = 0; p < 4; ++p) {
        float Ra = Rr[jlo[p]], Rb = Rr[jlo[p] + 1];
        float dm = (Ra + tyv[p] * (Rb - Ra)) * s3;

        float rx = (float)w * cW        + dm * kxc;   // ix + 0.5
        float ry = (float)(h0 + p) * cH + dm * kyc;   // iy + 0.5
        float ix = reflect_pre(rx, (float)W, twoW, invTwoW);
        float iy = reflect_pre(ry, (float)H, twoH, invTwoH);

        float x0f = floorf(ix), y0f = floorf(iy);
        wxv[p] = ix - x0f;
        wyv[p] = iy - y0f;
        int ix0 = (int)x0f;                 // in [0, W-1] after clip
        int jy0 = (int)y0f;
        int jy1 = min(jy0 + 1, H - 1);
        int qx  = min(ix0, W - 2);          // pair window always in-bounds
        CL[p] = (ix0 > qx);                 // ix0==W-1 -> wx==0, A:=texel W-1
        PA[p] = ibase + ((long long)jy0 * W + qx) * 3;
        PB[p] = ibase + ((long long)jy1 * W + qx) * 3;
    }

    // ---- stage 3: all 16 gathers issued before any use ----
    f4u va[4], vb[4]; f2u ua[4], ub[4];
    #pragma unroll
    for (int p = 0; p < 4; ++p) {
        va[p] = *(const f4u*)PA[p];
        ua[p] = *(const f2u*)(PA[p] + 4);
        vb[p] = *(const f4u*)PB[p];
        ub[p] = *(const f2u*)(PB[p] + 4);
    }
    __builtin_amdgcn_sched_barrier(0);      // pin: no blend hoisted between loads

    // ---- stage 4: blend + store ----
    long long obase = ((long long)(n * H + h0) * W + w) * 3;
    #pragma unroll
    for (int p = 0; p < 4; ++p) {
        float wx = wxv[p], wy = wyv[p];
        float wa = (1.0f - wx) * (1.0f - wy);
        float wb = wx * (1.0f - wy);
        float wc = (1.0f - wx) * wy;
        float wd = wx * wy;
        bool cl = CL[p];

        float A0 = cl ? va[p].w : va[p].x, A1 = cl ? ua[p].x : va[p].y, A2 = cl ? ua[p].y : va[p].z;
        float B0 = va[p].w,                B1 = ua[p].x,                B2 = ua[p].y;
        float C0 = cl ? vb[p].w : vb[p].x, C1 = cl ? ub[p].x : vb[p].y, C2 = cl ? ub[p].y : vb[p].z;
        float D0 = vb[p].w,                D1 = ub[p].x,                D2 = ub[p].y;

        float* o = out + obase + (long long)p * W * 3;
        o[0] = A0 * wa + B0 * wb + C0 * wc + D0 * wd;
        o[1] = A1 * wa + B1 * wb + C1 * wc + D1 * wd;
        o[2] = A2 * wa + B2 * wb + C2 * wc + D2 * wd;
    }
}

// ---------------- fallback: verified single-pixel kernel ----------------
__device__ __forceinline__ float reflect_coord(float x, float size) {
    x += 0.5f;
    float two = 2.0f * size;
    x = x - floorf(x / two) * two;
    if (x >= size) x = two - x;
    x -= 0.5f;
    return fminf(fmaxf(x, 0.0f), size - 1.0f);
}

__global__ __launch_bounds__(256) void displace_kernel(
    const float* __restrict__ img, const float* __restrict__ dmap,
    const float* __restrict__ amp, const float* __restrict__ ang,
    float* __restrict__ out, int N, int H, int W, int DH, int DW)
{
    long long idx = (long long)blockIdx.x * blockDim.x + threadIdx.x;
    long long total = (long long)N * H * W;
    if (idx >= total) return;
    int w = (int)(idx % W);
    long long t = idx / W;
    int h = (int)(t % H);
    int n = (int)(t / H);

    float sx = (w + 0.5f) * ((float)DW / (float)W) - 0.5f;
    float sy = (h + 0.5f) * ((float)DH / (float)H) - 0.5f;
    float fx = floorf(sx), fy = floorf(sy);
    float tx = sx - fx, ty = sy - fy;
    int dx0 = max(0, min(DW - 1, (int)fx));
    int dx1 = max(0, min(DW - 1, (int)fx + 1));
    int dy0 = max(0, min(DH - 1, (int)fy));
    int dy1 = max(0, min(DH - 1, (int)fy + 1));

    const float* dbase = dmap + (long long)n * DH * DW * 3;
    const float* p00 = dbase + ((long long)dy0 * DW + dx0) * 3;
    const float* p01 = dbase + ((long long)dy0 * DW + dx1) * 3;
    const float* p10 = dbase + ((long long)dy1 * DW + dx0) * 3;
    const float* p11 = dbase + ((long long)dy1 * DW + dx1) * 3;
    float m00 = p00[0] + p00[1] + p00[2];
    float m01 = p01[0] + p01[1] + p01[2];
    float m10 = p10[0] + p10[1] + p10[2];
    float m11 = p11[0] + p11[1] + p11[2];
    float dmv = ((m00 * (1.0f - tx) + m01 * tx) * (1.0f - ty)
               + (m10 * (1.0f - tx) + m11 * tx) * ty) * (1.0f / 3.0f);

    float a = amp[n];
    float sa, ca;
    sincosf(ang[n], &sa, &ca);
    float d = dmv * a;
    float ddx = ca * d * (2.0f / (float)(W - 1));
    float ddy = sa * d * (2.0f / (float)(H - 1));
    float gx = -1.0f + 2.0f * (float)w / (float)(W - 1) + ddx;
    float gy = -1.0f + 2.0f * (float)h / (float)(H - 1) + ddy;
    float ix = ((gx + 1.0f) * (float)W - 1.0f) * 0.5f;
    float iy = ((gy + 1.0f) * (float)H - 1.0f) * 0.5f;
    ix = reflect_coord(ix, (float)W);
    iy = reflect_coord(iy, (float)H);

    float x0f = floorf(ix), y0f = floorf(iy);
    float wx = ix - x0f, wy = iy - y0f;
    int ix0 = min((int)x0f, W - 1);
    int ix1 = min((int)x0f + 1, W - 1);
    int iy0 = min((int)y0f, H - 1);
    int iy1 = min((int)y0f + 1, H - 1);

    const float* ibase = img + (long long)n * H * W * 3;
    const float* Ia = ibase + ((long long)iy0 * W + ix0) * 3;
    const float* Ib = ibase + ((long long)iy0 * W + ix1) * 3;
    const float* Ic = ibase + ((long long)iy1 * W + ix0) * 3;
    const float* Id = ibase + ((long long)iy1 * W + ix1) * 3;
    float wa = (1.0f - wx) * (1.0f - wy);
    float wb = wx * (1.0f - wy);
    float wc = (1.0f - wx) * wy;
    float wd = wx * wy;
    float* o = out + idx * 3;
    #pragma unroll
    for (int c = 0; c < 3; ++c)
        o[c] = Ia[c] * wa + Ib[c] * wb + Ic[c] * wc + Id[c] * wd;
}

extern "C" void kernel_launch(void* const* d_in, const int* in_sizes, int n_in,
                              void* d_out, int out_size, void* d_ws, size_t ws_size,
                              hipStream_t stream) {
    const float* img  = (const float*)d_in[0];
    const float* dmap = (const float*)d_in[1];
    const float* amp  = (const float*)d_in[2];
    const float* ang  = (const float*)d_in[3];
    float* out = (float*)d_out;

    int N = in_sizes[2];
    long long hw  = (long long)in_sizes[0] / ((long long)N * 3);
    int H = (int)llround(sqrt((double)hw));
    int W = H;
    long long dhw = (long long)in_sizes[1] / ((long long)N * 3);
    int DH = (int)llround(sqrt((double)dhw));
    int DW = DH;

    bool fast = (W % 64 == 0) && (H % 16 == 0) && (W == 2 * DW) && (H == 2 * DH) &&
                (DW >= 2) && ((long long)H * W <= (long long)INT_MAX);

    if (fast) {
        int tiles_x = W / 64;
        int tiles_y = H / 16;
        int tpi = tiles_x * tiles_y;
        unsigned nb = (unsigned)((long long)tpi * N);
        displace_tile_kernel<<<nb, 256, 0, stream>>>(
            img, dmap, amp, ang, out, N, H, W, DH, DW, tiles_x, tpi, nb);
    } else {
        long long total = (long long)N * H * W;
        int block = 256;
        long long grid = (total + block - 1) / block;
        displace_kernel<<<(dim3)(unsigned)grid, block, 0, stream>>>(
            img, dmap, amp, ang, out, N, H, W, DH, DW);
    }
}